// Round 1
// baseline (246.467 us; speedup 1.0000x reference)
//
#include <hip/hip_runtime.h>

// SSIM loss, fused. Round 7: wave-autonomous full-row bands.
//  - THEORY: r6 was latency/sync-bound (VALUBusy 31%, HBM 27%, 8.7M LDS
//    bank-conflict cycles, 22 barriers/block). Remove LDS + barriers:
//    one wave64 owns a full 512-col row band; lane owns 8 contiguous cols;
//    vertical sliding sums live in registers (4 planes: Sx, Sy, Sxx+Syy
//    merged, Sxy = 32 VGPR); horizontal 7-window halo = 6 shfl_down(.,1)
//    per plane (conflict-free crossbar, no LDS storage, no barriers).
//  - Loads: retire-row loads issued FIRST, next-new-row loads second, both
//    before the ~500-cyc horizontal phase. Compiler's counted vmcnt before
//    the retire-subtract drains only the retire loads; next-row (HBM
//    latency) loads stay in flight across the iteration boundary.
//  - Band = 11 rows -> 46 bands x 96 imgs = 4416 waves (1104 blocks of 4
//    independent waves). Adjacent bands sit in the same block -> halo rows
//    shared in the same CU's caches.

#define IW    512
#define OUTW  506
#define BAND  11                 // output rows per wave; 46*11 = 506 exactly
#define NBANDS 46
#define NIMG  96
#define WPB   4                  // independent waves per block
#define NBLK  (NBANDS * NIMG / WPB)   // 1104 blocks
#define NPART NBLK
#define C1N2  0.2401f            // 1e-4 * 49^2
#define C2N2  2.1609f            // 9e-4 * 49^2
#define KA    (49.0f/24.0f)
#define KB    (49.0f/48.0f)
#define TOTAL_OUT 24579456.0f    // 96*506*506

// W's are raw 49-px sums; S2 = Sxx + Syy (only ever consumed as the sum).
__device__ __forceinline__ float ssim_raw(float Sx, float Sy, float S2, float Sxy) {
    float sxsy = Sx * Sy;
    float p    = fmaf(Sx, Sx, Sy * Sy);
    float a1   = fmaf(2.0f, sxsy, C1N2);
    float b1   = p + C1N2;
    float a2   = fmaf(KA, fmaf(49.0f, Sxy, -sxsy), C2N2);
    float b2   = fmaf(KB, fmaf(49.0f, S2, -p), C2N2);
    return (a1 * a2) * __builtin_amdgcn_rcpf(b1 * b2);
}

__device__ __forceinline__ void unpack8(float4 a, float4 b, float* d) {
    d[0]=a.x; d[1]=a.y; d[2]=a.z; d[3]=a.w;
    d[4]=b.x; d[5]=b.y; d[6]=b.z; d[7]=b.w;
}

__global__ __launch_bounds__(256, 4) void ssim_main(const float* __restrict__ X,
                                                    const float* __restrict__ Y,
                                                    float* __restrict__ partials) {
    __shared__ float wsum[WPB];
    const int t    = threadIdx.x;
    const int wv   = t >> 6;
    const int lane = t & 63;
    const int gw   = blockIdx.x * WPB + wv;      // 0..4415
    const int img  = gw / NBANDS;
    const int band = gw - img * NBANDS;
    const int r0   = band * BAND;
    const float4* X4 = (const float4*)X + (size_t)img * (IW * IW / 4);
    const float4* Y4 = (const float4*)Y + (size_t)img * (IW * IW / 4);
    const int c0 = 2 * lane;                     // float4 index of col 8*lane

    // vertical sliding column sums, 8 cols/lane, 4 planes = 32 VGPR
    float sx[8], sy[8], s2[8], sxy[8];
#pragma unroll
    for (int q = 0; q < 8; ++q) { sx[q]=0.f; sy[q]=0.f; s2[q]=0.f; sxy[q]=0.f; }

    // prologue: rows r0 .. r0+5
#pragma unroll
    for (int i = 0; i < 6; ++i) {
        const int ro = (r0 + i) * (IW / 4);
        float4 xa = X4[ro + c0], xb = X4[ro + c0 + 1];
        float4 ya = Y4[ro + c0], yb = Y4[ro + c0 + 1];
        float x[8], y[8];
        unpack8(xa, xb, x); unpack8(ya, yb, y);
#pragma unroll
        for (int q = 0; q < 8; ++q) {
            sx[q] += x[q]; sy[q] += y[q];
            s2[q]  = fmaf(x[q], x[q], s2[q]);
            s2[q]  = fmaf(y[q], y[q], s2[q]);
            sxy[q] = fmaf(x[q], y[q], sxy[q]);
        }
    }

    // prefetch new row for r=0 (input row r0+6)
    int rn = (r0 + 6) * (IW / 4);
    float4 nxa = X4[rn + c0], nxb = X4[rn + c0 + 1];
    float4 nya = Y4[rn + c0], nyb = Y4[rn + c0 + 1];

    float accS = 0.0f;

#pragma unroll 1
    for (int r = 0; r < BAND; ++r) {
        // vertical add of prefetched new row -> window rows [r0+r .. r0+r+6]
        {
            float x[8], y[8];
            unpack8(nxa, nxb, x); unpack8(nya, nyb, y);
#pragma unroll
            for (int q = 0; q < 8; ++q) {
                sx[q] += x[q]; sy[q] += y[q];
                s2[q]  = fmaf(x[q], x[q], s2[q]);
                s2[q]  = fmaf(y[q], y[q], s2[q]);
                sxy[q] = fmaf(x[q], y[q], sxy[q]);
            }
        }
        // issue retire loads (row r0+r, cache-warm) FIRST, then next new row
        // (HBM). vsub's counted vmcnt drains only the retire loads; the next
        // row stays in flight across the iteration boundary.
        const int rr = (r0 + r) * (IW / 4);
        float4 rxa = X4[rr + c0], rxb = X4[rr + c0 + 1];
        float4 rya = Y4[rr + c0], ryb = Y4[rr + c0 + 1];
        rn = ((r < BAND - 1) ? (r0 + 7 + r) : (r0 + 6)) * (IW / 4);
        nxa = X4[rn + c0]; nxb = X4[rn + c0 + 1];
        nya = Y4[rn + c0]; nyb = Y4[rn + c0 + 1];

        // horizontal 7-windows: halo = neighbor lane's first 6 col sums
        float Wx[8], Wy[8], W2[8], Wxy[8];
#define HWIN(S, W)                                                         \
        {                                                                  \
            float h0 = __shfl_down(S[0], 1, 64);                           \
            float h1 = __shfl_down(S[1], 1, 64);                           \
            float h2 = __shfl_down(S[2], 1, 64);                           \
            float h3 = __shfl_down(S[3], 1, 64);                           \
            float h4 = __shfl_down(S[4], 1, 64);                           \
            float h5 = __shfl_down(S[5], 1, 64);                           \
            W[0] = ((S[0]+S[1]) + (S[2]+S[3])) + ((S[4]+S[5]) + S[6]);     \
            W[1] = W[0] + (S[7] - S[0]);                                   \
            W[2] = W[1] + (h0   - S[1]);                                   \
            W[3] = W[2] + (h1   - S[2]);                                   \
            W[4] = W[3] + (h2   - S[3]);                                   \
            W[5] = W[4] + (h3   - S[4]);                                   \
            W[6] = W[5] + (h4   - S[5]);                                   \
            W[7] = W[6] + (h5   - S[6]);                                   \
        }
        HWIN(sx,  Wx)
        HWIN(sy,  Wy)
        HWIN(s2,  W2)
        HWIN(sxy, Wxy)
#undef HWIN

        // SSIM at 8 output cols (lane 63: only m<2 valid; its halo is
        // shfl-clamped own data -> finite, masked out by the select)
#pragma unroll
        for (int m = 0; m < 8; ++m) {
            float Sv = ssim_raw(Wx[m], Wy[m], W2[m], Wxy[m]);
            accS += (8 * lane + m < OUTW) ? Sv : 0.0f;
        }

        // retire oldest row
        {
            float x[8], y[8];
            unpack8(rxa, rxb, x); unpack8(rya, ryb, y);
#pragma unroll
            for (int q = 0; q < 8; ++q) {
                sx[q] -= x[q]; sy[q] -= y[q];
                s2[q]  = fmaf(-x[q], x[q], s2[q]);
                s2[q]  = fmaf(-y[q], y[q], s2[q]);
                sxy[q] = fmaf(-x[q], y[q], sxy[q]);
            }
        }
    }

    // block reduce -> one partial per block
#pragma unroll
    for (int o = 32; o > 0; o >>= 1)
        accS += __shfl_down(accS, o, 64);
    if (lane == 0) wsum[wv] = accS;
    __syncthreads();
    if (t == 0)
        partials[blockIdx.x] = (wsum[0] + wsum[1]) + (wsum[2] + wsum[3]);
}

__global__ __launch_bounds__(256) void ssim_finalize(const float* __restrict__ partials,
                                                     float* __restrict__ out) {
    __shared__ float wsum[4];
    const int t = threadIdx.x;
    float v = 0.0f;
    for (int i = t; i < NPART; i += 256) v += partials[i];
#pragma unroll
    for (int o = 32; o > 0; o >>= 1)
        v += __shfl_down(v, o, 64);
    if ((t & 63) == 0) wsum[t >> 6] = v;
    __syncthreads();
    if (t == 0)
        out[0] = 1.0f - ((wsum[0] + wsum[1]) + (wsum[2] + wsum[3])) / TOTAL_OUT;
}

extern "C" void kernel_launch(void* const* d_in, const int* in_sizes, int n_in,
                              void* d_out, int out_size, void* d_ws, size_t ws_size,
                              hipStream_t stream) {
    const float* X = (const float*)d_in[0];
    const float* Y = (const float*)d_in[1];
    float* partials = (float*)d_ws;          // NPART floats (4.4 KB)
    float* out = (float*)d_out;

    hipLaunchKernelGGL(ssim_main, dim3(NBLK), dim3(256), 0, stream,
                       X, Y, partials);
    hipLaunchKernelGGL(ssim_finalize, dim3(1), dim3(256), 0, stream,
                       partials, out);
}